// Round 8
// baseline (129.980 us; speedup 1.0000x reference)
//
#include <hip/hip_runtime.h>
#include <hip/hip_bf16.h>

typedef __bf16 bf16_t;
typedef __bf16 bf16x8 __attribute__((ext_vector_type(8)));
typedef float f32x4 __attribute__((ext_vector_type(4)));

static constexpr int NB  = 4096;  // batch
static constexpr int KIN = 768;   // D_IN
static constexpr int DD  = 256;   // D

// ---------------------------------------------------------------------------
// Kernel 1: pack W (KIN x DD, f32) -> Wt (DD x KIN, bf16) via LDS transpose.
// ---------------------------------------------------------------------------
__global__ __launch_bounds__(256) void pack_wt_kernel(
    const float* __restrict__ Wi, const float* __restrict__ Wx,
    bf16_t* __restrict__ Oi, bf16_t* __restrict__ Ox)
{
  __shared__ bf16_t tile[64][66];
  const int b = blockIdx.x;
  const bool isTxt = (b >= 48);
  const int t = isTxt ? b - 48 : b;
  const float* W = isTxt ? Wx : Wi;
  bf16_t* O      = isTxt ? Ox : Oi;
  const int k0 = (t % 12) * 64;     // KIN/64 = 12
  const int c0 = (t / 12) * 64;     // DD/64  = 4
  const int cl = threadIdx.x & 63;
  const int rw = threadIdx.x >> 6;

#pragma unroll
  for (int p = 0; p < 16; ++p) {
    const int kl = p * 4 + rw;
    tile[kl][cl] = (bf16_t)W[(size_t)(k0 + kl) * DD + c0 + cl];
  }
  __syncthreads();
#pragma unroll
  for (int p = 0; p < 16; ++p) {
    const int clo = p * 4 + rw;
    O[(size_t)(c0 + clo) * KIN + k0 + cl] = tile[cl][clo];
  }
}

// ---------------------------------------------------------------------------
// Kernel 2: projection GEMM  F = X @ W + b   (4096 x 768 x 256), bf16 MFMA.
// 512 blocks x 512 threads (8 waves). Block = 16 rows; wave w = cols
// [w*32, w*32+32) -> 16 waves/CU for latency hiding on the HBM-cold X loads.
// Per-row 1/||f|| and strength dot reduced via shfl + LDS across 8 waves.
// ---------------------------------------------------------------------------
__global__ __launch_bounds__(512) void proj_kernel(
    const float* __restrict__ images, const float* __restrict__ texts,
    const bf16_t* __restrict__ Wti, const bf16_t* __restrict__ Wtt,
    const float* __restrict__ b_img, const float* __restrict__ b_txt,
    const float* __restrict__ cs_w,
    bf16_t* __restrict__ Fi, bf16_t* __restrict__ Ft,
    float* __restrict__ rni, float* __restrict__ si,
    float* __restrict__ rnt, float* __restrict__ st)
{
  __shared__ float lnsq[8][16];
  __shared__ float lsdt[8][16];

  const int bid = blockIdx.x;
  const bool isTxt = (bid >= 256);
  const float* X    = isTxt ? texts : images;
  const bf16_t* Wt  = isTxt ? Wtt : Wti;
  const float* bias = isTxt ? b_txt : b_img;
  const float* csw  = cs_w + (isTxt ? DD : 0);
  bf16_t* F     = isTxt ? Ft : Fi;
  float* rnorm  = isTxt ? rnt : rni;
  float* svec   = isTxt ? st : si;

  const int tid  = threadIdx.x;
  const int lane = tid & 63;
  const int wave = tid >> 6;       // 0..7
  const int lrow = lane & 15;
  const int g    = lane >> 4;
  const int rb   = (bid & 255) * 16;   // block's 16 rows
  const int cwb  = wave * 32;          // wave's 32 cols

  const f32x4 fzero = {0.f, 0.f, 0.f, 0.f};
  f32x4 acc[2];
#pragma unroll
  for (int n = 0; n < 2; ++n) acc[n] = fzero;

  const float*  xp0 = X  + (size_t)(rb + lrow) * KIN + g * 8;
  const bf16_t* wp0 = Wt + (size_t)(cwb + lrow) * KIN + g * 8;

#pragma unroll 2
  for (int ks = 0; ks < KIN / 32; ++ks) {
    const float* xp = xp0 + ks * 32;
    f32x4 x0 = *reinterpret_cast<const f32x4*>(xp);
    f32x4 x1 = *reinterpret_cast<const f32x4*>(xp + 4);
    bf16x8 a;
#pragma unroll
    for (int e = 0; e < 4; ++e) { a[e] = (bf16_t)x0[e]; a[e + 4] = (bf16_t)x1[e]; }
#pragma unroll
    for (int n = 0; n < 2; ++n) {
      bf16x8 bfr = *reinterpret_cast<const bf16x8*>(wp0 + (size_t)n * 16 * KIN + ks * 32);
      acc[n] = __builtin_amdgcn_mfma_f32_16x16x32_bf16(a, bfr, acc[n], 0, 0, 0);
    }
  }

  float nsq[4] = {0.f, 0.f, 0.f, 0.f};
  float sdt[4] = {0.f, 0.f, 0.f, 0.f};
#pragma unroll
  for (int n = 0; n < 2; ++n) {
    const int col = cwb + n * 16 + lrow;
    const float bn = bias[col];
    const float wn = csw[col];
#pragma unroll
    for (int r = 0; r < 4; ++r) {
      float v = acc[n][r] + bn;
      const int row = rb + g * 4 + r;
      F[(size_t)row * DD + col] = (bf16_t)v;
      nsq[r] += v * v;
      sdt[r] += v * wn;
    }
  }
#pragma unroll
  for (int msk = 8; msk >= 1; msk >>= 1) {
#pragma unroll
    for (int r = 0; r < 4; ++r) {
      nsq[r] += __shfl_xor(nsq[r], msk, 64);
      sdt[r] += __shfl_xor(sdt[r], msk, 64);
    }
  }
  if (lrow == 0) {
#pragma unroll
    for (int r = 0; r < 4; ++r) {
      lnsq[wave][g * 4 + r] = nsq[r];
      lsdt[wave][g * 4 + r] = sdt[r];
    }
  }
  __syncthreads();
  if (tid < 16) {
    float tn = 0.f, ts = 0.f;
#pragma unroll
    for (int w2 = 0; w2 < 8; ++w2) { tn += lnsq[w2][tid]; ts += lsdt[w2][tid]; }
    rnorm[rb + tid] = 1.0f / sqrtf(tn);
    svec [rb + tid] = ts;
  }
}

// ---------------------------------------------------------------------------
// Kernel 3: sim = Fi @ Ft^T (4096 x 4096 x 256) + fused epilogue.
// 128x128 tile, 1024 blocks, 4 waves. Each wave's fragment rows SPAN both
// 64-row halves (rows wr*32.. and 64+wr*32..) so the LDS bounce buffer is
// only 64x128 f32 = 32 KB -> 4 blocks/CU (2x the streaming concurrency of
// the 64 KB version). Per half: all-wave frag write -> barrier -> pure
// streaming (f32x4 NT edge load + 3x f32x4 NT stores).
// ---------------------------------------------------------------------------
__global__ __launch_bounds__(256) void sim_kernel(
    const bf16_t* __restrict__ Fi, const bf16_t* __restrict__ Ft,
    const float* __restrict__ rni, const float* __restrict__ si,
    const float* __restrict__ rnt, const float* __restrict__ st,
    const float* __restrict__ cs_b, const float* __restrict__ edge,
    float* __restrict__ out_final, float* __restrict__ out_sim,
    float* __restrict__ out_causal)
{
  __shared__ float smem[64 * 128];   // 32 KB, XOR-swizzled

  // XCD-aware swizzle: 1024 blocks, 8 XCDs -> contiguous 128-block chunks.
  const int bid = blockIdx.x;
  const int swz = (bid & 7) * 128 + (bid >> 3);
  const int bx = swz & 31;   // col tile
  const int by = swz >> 5;   // row tile

  const int tid  = threadIdx.x;
  const int lane = tid & 63;
  const int wave = tid >> 6;
  const int wr = wave >> 1;
  const int wc = wave & 1;
  const int lrow = lane & 15;
  const int g    = lane >> 4;

  const int rowG0 = by * 128;
  const int colG0 = bx * 128;
  const int colBase = colG0 + wc * 64;

  const f32x4 fzero = {0.f, 0.f, 0.f, 0.f};
  f32x4 acc[4][4];   // m: row sub-tile (m>>1 = half, m&1 = 16-row step)
#pragma unroll
  for (int m = 0; m < 4; ++m)
#pragma unroll
    for (int n = 0; n < 4; ++n) acc[m][n] = fzero;

  // A rows for m: rowG0 + (m>>1)*64 + wr*32 + (m&1)*16
  const bf16_t* apL = Fi + (size_t)(rowG0 + wr * 32 + lrow) * DD + g * 8;
  const bf16_t* apH = apL + (size_t)64 * DD;
  const bf16_t* bp0 = Ft + (size_t)(colBase + lrow) * DD + g * 8;

#pragma unroll 2
  for (int ks = 0; ks < DD / 32; ++ks) {
    bf16x8 a[4], b[4];
    a[0] = *reinterpret_cast<const bf16x8*>(apL + ks * 32);
    a[1] = *reinterpret_cast<const bf16x8*>(apL + (size_t)16 * DD + ks * 32);
    a[2] = *reinterpret_cast<const bf16x8*>(apH + ks * 32);
    a[3] = *reinterpret_cast<const bf16x8*>(apH + (size_t)16 * DD + ks * 32);
#pragma unroll
    for (int n = 0; n < 4; ++n)
      b[n] = *reinterpret_cast<const bf16x8*>(bp0 + (size_t)n * 16 * DD + ks * 32);
#pragma unroll
    for (int m = 0; m < 4; ++m)
#pragma unroll
      for (int n = 0; n < 4; ++n)
        acc[m][n] = __builtin_amdgcn_mfma_f32_16x16x32_bf16(a[m], b[n], acc[m][n], 0, 0, 0);
  }

  const float cb = cs_b[0];
  float rntv[4];
#pragma unroll
  for (int n = 0; n < 4; ++n) rntv[n] = rnt[colBase + n * 16 + lrow];

#pragma unroll
  for (int h = 0; h < 2; ++h) {
    // ---- fragment write: all 4 waves write their 32 rows of this half ----
#pragma unroll
    for (int m2 = 0; m2 < 2; ++m2) {
      const int m = h * 2 + m2;
      const int rbase = wr * 32 + m2 * 16 + g * 4;   // local row base (0..63)
      float rn[4];
#pragma unroll
      for (int r = 0; r < 4; ++r) rn[r] = rni[rowG0 + h * 64 + rbase + r];
#pragma unroll
      for (int n = 0; n < 4; ++n) {
        const int cl = wc * 64 + n * 16 + lrow;
#pragma unroll
        for (int r = 0; r < 4; ++r) {
          const int rl = rbase + r;
          smem[rl * 128 + (cl ^ ((rl & 7) << 2))] = acc[m][n][r] * rn[r] * rntv[n];
        }
      }
    }
    __syncthreads();

    // ---- streaming epilogue for this half: 8192 elems = 256 thr x 8 x f32x4
#pragma unroll 4
    for (int it = 0; it < 8; ++it) {
      const int e  = (it * 256 + tid) * 4;
      const int r0 = e >> 7;        // 0..63
      const int c  = e & 127;       // multiple of 4
      const int grow = rowG0 + h * 64 + r0;
      const size_t idx = (size_t)grow * NB + colG0 + c;
      const f32x4 ew4 = __builtin_nontemporal_load(reinterpret_cast<const f32x4*>(edge + idx));
      const f32x4 sv4 = *reinterpret_cast<const f32x4*>(&smem[r0 * 128 + (c ^ ((r0 & 7) << 2))]);
      const float sir = si[grow];
      const f32x4 st4 = *reinterpret_cast<const f32x4*>(st + colG0 + c);
      f32x4 ca4, fin4;
#pragma unroll
      for (int j = 0; j < 4; ++j) {
        const float strength = sir + st4[j] + cb;
        ca4[j]  = ew4[j] * strength;
        fin4[j] = sv4[j] + 0.3f * ca4[j];
      }
      __builtin_nontemporal_store(sv4,  reinterpret_cast<f32x4*>(out_sim    + idx));
      __builtin_nontemporal_store(ca4,  reinterpret_cast<f32x4*>(out_causal + idx));
      __builtin_nontemporal_store(fin4, reinterpret_cast<f32x4*>(out_final  + idx));
    }
    if (h == 0) __syncthreads();   // LDS reuse: drain reads before half-1 writes
  }
}

// ---------------------------------------------------------------------------
extern "C" void kernel_launch(void* const* d_in, const int* in_sizes, int n_in,
                              void* d_out, int out_size, void* d_ws, size_t ws_size,
                              hipStream_t stream) {
  const float* images = (const float*)d_in[0];
  const float* texts  = (const float*)d_in[1];
  const float* W_img  = (const float*)d_in[2];
  const float* b_img  = (const float*)d_in[3];
  const float* W_txt  = (const float*)d_in[4];
  const float* b_txt  = (const float*)d_in[5];
  const float* cs_w   = (const float*)d_in[6];
  const float* cs_b   = (const float*)d_in[7];
  const float* edge   = (const float*)d_in[8];

  float* out_final  = (float*)d_out;
  float* out_sim    = out_final + (size_t)NB * NB;
  float* out_causal = out_sim   + (size_t)NB * NB;

  // Workspace layout (~4.9 MiB total)
  char* ws = (char*)d_ws;
  bf16_t* Fi  = (bf16_t*)ws;                     // 4096*256 bf16
  bf16_t* Ft  = Fi  + (size_t)NB * DD;           // 4096*256 bf16
  bf16_t* Wti = Ft  + (size_t)NB * DD;           // 256*768 bf16
  bf16_t* Wtt = Wti + (size_t)DD * KIN;          // 256*768 bf16
  float*  rni = (float*)(Wtt + (size_t)DD * KIN);
  float*  siv = rni + NB;
  float*  rnt = siv + NB;
  float*  stv = rnt + NB;

  pack_wt_kernel<<<96, 256, 0, stream>>>(W_img, W_txt, Wti, Wtt);
  proj_kernel<<<512, 512, 0, stream>>>(images, texts, Wti, Wtt, b_img, b_txt, cs_w,
                                       Fi, Ft, rni, siv, rnt, stv);
  sim_kernel<<<1024, 256, 0, stream>>>(Fi, Ft, rni, siv, rnt, stv, cs_b, edge,
                                       out_final, out_sim, out_causal);
}

// Round 9
// 114.781 us; speedup vs baseline: 1.1324x; 1.1324x over previous
//
#include <hip/hip_runtime.h>
#include <hip/hip_bf16.h>

typedef __bf16 bf16_t;
typedef __bf16 bf16x8 __attribute__((ext_vector_type(8)));
typedef float f32x4 __attribute__((ext_vector_type(4)));

static constexpr int NB  = 4096;  // batch
static constexpr int KIN = 768;   // D_IN
static constexpr int DD  = 256;   // D

// ---------------------------------------------------------------------------
// Kernel 1: pack W (KIN x DD, f32) -> Wt (DD x KIN, bf16) via LDS transpose.
// ---------------------------------------------------------------------------
__global__ __launch_bounds__(256) void pack_wt_kernel(
    const float* __restrict__ Wi, const float* __restrict__ Wx,
    bf16_t* __restrict__ Oi, bf16_t* __restrict__ Ox)
{
  __shared__ bf16_t tile[64][66];
  const int b = blockIdx.x;
  const bool isTxt = (b >= 48);
  const int t = isTxt ? b - 48 : b;
  const float* W = isTxt ? Wx : Wi;
  bf16_t* O      = isTxt ? Ox : Oi;
  const int k0 = (t % 12) * 64;     // KIN/64 = 12
  const int c0 = (t / 12) * 64;     // DD/64  = 4
  const int cl = threadIdx.x & 63;
  const int rw = threadIdx.x >> 6;

#pragma unroll
  for (int p = 0; p < 16; ++p) {
    const int kl = p * 4 + rw;
    tile[kl][cl] = (bf16_t)W[(size_t)(k0 + kl) * DD + c0 + cl];
  }
  __syncthreads();
#pragma unroll
  for (int p = 0; p < 16; ++p) {
    const int clo = p * 4 + rw;
    O[(size_t)(c0 + clo) * KIN + k0 + cl] = tile[cl][clo];
  }
}

// ---------------------------------------------------------------------------
// Kernel 2: projection GEMM  F = X @ W + b   (4096 x 768 x 256), bf16 MFMA.
// 512 blocks (256 per matrix). Block = 16 rows; wave w = cols [w*64, w*64+64).
// ---------------------------------------------------------------------------
__global__ __launch_bounds__(256) void proj_kernel(
    const float* __restrict__ images, const float* __restrict__ texts,
    const bf16_t* __restrict__ Wti, const bf16_t* __restrict__ Wtt,
    const float* __restrict__ b_img, const float* __restrict__ b_txt,
    const float* __restrict__ cs_w,
    bf16_t* __restrict__ Fi, bf16_t* __restrict__ Ft,
    float* __restrict__ rni, float* __restrict__ si,
    float* __restrict__ rnt, float* __restrict__ st)
{
  __shared__ float lnsq[4][16];
  __shared__ float lsdt[4][16];

  const int bid = blockIdx.x;
  const bool isTxt = (bid >= 256);
  const float* X    = isTxt ? texts : images;
  const bf16_t* Wt  = isTxt ? Wtt : Wti;
  const float* bias = isTxt ? b_txt : b_img;
  const float* csw  = cs_w + (isTxt ? DD : 0);
  bf16_t* F     = isTxt ? Ft : Fi;
  float* rnorm  = isTxt ? rnt : rni;
  float* svec   = isTxt ? st : si;

  const int lane = threadIdx.x & 63;
  const int wave = threadIdx.x >> 6;
  const int lrow = lane & 15;
  const int g    = lane >> 4;
  const int rb   = (bid & 255) * 16;
  const int cwb  = wave * 64;

  const f32x4 fzero = {0.f, 0.f, 0.f, 0.f};
  f32x4 acc[4];
#pragma unroll
  for (int n = 0; n < 4; ++n) acc[n] = fzero;

  const float*  xp0 = X  + (size_t)(rb + lrow) * KIN + g * 8;
  const bf16_t* wp0 = Wt + (size_t)(cwb + lrow) * KIN + g * 8;

#pragma unroll 2
  for (int ks = 0; ks < KIN / 32; ++ks) {
    const float* xp = xp0 + ks * 32;
    f32x4 x0 = *reinterpret_cast<const f32x4*>(xp);
    f32x4 x1 = *reinterpret_cast<const f32x4*>(xp + 4);
    bf16x8 a;
#pragma unroll
    for (int e = 0; e < 4; ++e) { a[e] = (bf16_t)x0[e]; a[e + 4] = (bf16_t)x1[e]; }
#pragma unroll
    for (int n = 0; n < 4; ++n) {
      bf16x8 bfr = *reinterpret_cast<const bf16x8*>(wp0 + (size_t)n * 16 * KIN + ks * 32);
      acc[n] = __builtin_amdgcn_mfma_f32_16x16x32_bf16(a, bfr, acc[n], 0, 0, 0);
    }
  }

  float nsq[4] = {0.f, 0.f, 0.f, 0.f};
  float sdt[4] = {0.f, 0.f, 0.f, 0.f};
#pragma unroll
  for (int n = 0; n < 4; ++n) {
    const int col = cwb + n * 16 + lrow;
    const float bn = bias[col];
    const float wn = csw[col];
#pragma unroll
    for (int r = 0; r < 4; ++r) {
      float v = acc[n][r] + bn;
      const int row = rb + g * 4 + r;
      F[(size_t)row * DD + col] = (bf16_t)v;
      nsq[r] += v * v;
      sdt[r] += v * wn;
    }
  }
#pragma unroll
  for (int msk = 8; msk >= 1; msk >>= 1) {
#pragma unroll
    for (int r = 0; r < 4; ++r) {
      nsq[r] += __shfl_xor(nsq[r], msk, 64);
      sdt[r] += __shfl_xor(sdt[r], msk, 64);
    }
  }
  if (lrow == 0) {
#pragma unroll
    for (int r = 0; r < 4; ++r) {
      lnsq[wave][g * 4 + r] = nsq[r];
      lsdt[wave][g * 4 + r] = sdt[r];
    }
  }
  __syncthreads();
  if (threadIdx.x < 16) {
    float tn = 0.f, ts = 0.f;
#pragma unroll
    for (int w2 = 0; w2 < 4; ++w2) { tn += lnsq[w2][threadIdx.x]; ts += lsdt[w2][threadIdx.x]; }
    rnorm[rb + threadIdx.x] = 1.0f / sqrtf(tn);
    svec [rb + threadIdx.x] = ts;
  }
}

// ---------------------------------------------------------------------------
// Kernel 3: sim = Fi @ Ft^T (4096 x 4096 x 256) + fused epilogue.
// 128x128 tile, 1024 blocks, 4 waves (2x2) x 4x4 fragments. Sim values
// bounce through a 64KB XOR-swizzled LDS tile; the epilogue is a pure
// streaming phase. R9 change vs R7: output stores are PLAIN (not NT) so the
// L2 write-back path absorbs store bursts (fillBuffer-style, 7 TB/s);
// only the L3-resident edge read stays nontemporal.
// ---------------------------------------------------------------------------
__global__ __launch_bounds__(256) void sim_kernel(
    const bf16_t* __restrict__ Fi, const bf16_t* __restrict__ Ft,
    const float* __restrict__ rni, const float* __restrict__ si,
    const float* __restrict__ rnt, const float* __restrict__ st,
    const float* __restrict__ cs_b, const float* __restrict__ edge,
    float* __restrict__ out_final, float* __restrict__ out_sim,
    float* __restrict__ out_causal)
{
  extern __shared__ float smem[];   // 128*128 f32 = 64 KB, XOR-swizzled

  // XCD-aware swizzle: 1024 blocks, 8 XCDs -> contiguous 128-block chunks.
  const int bid = blockIdx.x;
  const int swz = (bid & 7) * 128 + (bid >> 3);
  const int bx = swz & 31;   // col tile
  const int by = swz >> 5;   // row tile

  const int lane = threadIdx.x & 63;
  const int wave = threadIdx.x >> 6;
  const int wr = wave >> 1;
  const int wc = wave & 1;
  const int lrow = lane & 15;
  const int g    = lane >> 4;

  const int rowBase = by * 128 + wr * 64;
  const int colBase = bx * 128 + wc * 64;

  const f32x4 fzero = {0.f, 0.f, 0.f, 0.f};
  f32x4 acc[4][4];
#pragma unroll
  for (int m = 0; m < 4; ++m)
#pragma unroll
    for (int n = 0; n < 4; ++n) acc[m][n] = fzero;

  const bf16_t* ap0 = Fi + (size_t)(rowBase + lrow) * DD + g * 8;
  const bf16_t* bp0 = Ft + (size_t)(colBase + lrow) * DD + g * 8;

#pragma unroll 2
  for (int ks = 0; ks < DD / 32; ++ks) {
    bf16x8 a[4], b[4];
#pragma unroll
    for (int m = 0; m < 4; ++m)
      a[m] = *reinterpret_cast<const bf16x8*>(ap0 + (size_t)m * 16 * DD + ks * 32);
#pragma unroll
    for (int n = 0; n < 4; ++n)
      b[n] = *reinterpret_cast<const bf16x8*>(bp0 + (size_t)n * 16 * DD + ks * 32);
#pragma unroll
    for (int m = 0; m < 4; ++m)
#pragma unroll
      for (int n = 0; n < 4; ++n)
        acc[m][n] = __builtin_amdgcn_mfma_f32_16x16x32_bf16(a[m], b[n], acc[m][n], 0, 0, 0);
  }

  // Scale factors for this wave's fragments.
  float rntv[4];
#pragma unroll
  for (int n = 0; n < 4; ++n) rntv[n] = rnt[colBase + n * 16 + lrow];
  float rnv[4][4];
#pragma unroll
  for (int m = 0; m < 4; ++m)
#pragma unroll
    for (int r = 0; r < 4; ++r) rnv[m][r] = rni[rowBase + m * 16 + g * 4 + r];

  // Fragment -> LDS (final sim values). XOR swizzle: col ^= (row&7)<<2.
#pragma unroll
  for (int m = 0; m < 4; ++m) {
#pragma unroll
    for (int n = 0; n < 4; ++n) {
#pragma unroll
      for (int r = 0; r < 4; ++r) {
        const int rl = wr * 64 + m * 16 + g * 4 + r;      // tile-local row
        const int cl = wc * 64 + n * 16 + lrow;           // tile-local col
        smem[rl * 128 + (cl ^ ((rl & 7) << 2))] = acc[m][n][r] * rnv[m][r] * rntv[n];
      }
    }
  }
  __syncthreads();

  // Streaming epilogue: 16384 elems = 256 thr x 16 iters x float4.
  const float cb = cs_b[0];
  const int rowG0 = by * 128;
  const int colG0 = bx * 128;
#pragma unroll 4
  for (int it = 0; it < 16; ++it) {
    const int e = (it * 256 + threadIdx.x) * 4;
    const int r = e >> 7;        // 0..127
    const int c = e & 127;       // 0..124, multiple of 4
    const f32x4 sv4 = *reinterpret_cast<const f32x4*>(&smem[r * 128 + (c ^ ((r & 7) << 2))]);
    const float sir = si[rowG0 + r];
    const f32x4 st4 = *reinterpret_cast<const f32x4*>(st + colG0 + c);
    const size_t idx = (size_t)(rowG0 + r) * NB + colG0 + c;
    const f32x4 ew4 = __builtin_nontemporal_load(reinterpret_cast<const f32x4*>(edge + idx));
    f32x4 ca4, fin4;
#pragma unroll
    for (int j = 0; j < 4; ++j) {
      const float strength = sir + st4[j] + cb;
      ca4[j]  = ew4[j] * strength;
      fin4[j] = sv4[j] + 0.3f * ca4[j];
    }
    *reinterpret_cast<f32x4*>(out_sim    + idx) = sv4;
    *reinterpret_cast<f32x4*>(out_causal + idx) = ca4;
    *reinterpret_cast<f32x4*>(out_final  + idx) = fin4;
  }
}

// ---------------------------------------------------------------------------
extern "C" void kernel_launch(void* const* d_in, const int* in_sizes, int n_in,
                              void* d_out, int out_size, void* d_ws, size_t ws_size,
                              hipStream_t stream) {
  const float* images = (const float*)d_in[0];
  const float* texts  = (const float*)d_in[1];
  const float* W_img  = (const float*)d_in[2];
  const float* b_img  = (const float*)d_in[3];
  const float* W_txt  = (const float*)d_in[4];
  const float* b_txt  = (const float*)d_in[5];
  const float* cs_w   = (const float*)d_in[6];
  const float* cs_b   = (const float*)d_in[7];
  const float* edge   = (const float*)d_in[8];

  float* out_final  = (float*)d_out;
  float* out_sim    = out_final + (size_t)NB * NB;
  float* out_causal = out_sim   + (size_t)NB * NB;

  // Workspace layout (~4.9 MiB total)
  char* ws = (char*)d_ws;
  bf16_t* Fi  = (bf16_t*)ws;                     // 4096*256 bf16
  bf16_t* Ft  = Fi  + (size_t)NB * DD;           // 4096*256 bf16
  bf16_t* Wti = Ft  + (size_t)NB * DD;           // 256*768 bf16
  bf16_t* Wtt = Wti + (size_t)DD * KIN;          // 256*768 bf16
  float*  rni = (float*)(Wtt + (size_t)DD * KIN);
  float*  siv = rni + NB;
  float*  rnt = siv + NB;
  float*  stv = rnt + NB;

  pack_wt_kernel<<<96, 256, 0, stream>>>(W_img, W_txt, Wti, Wtt);
  proj_kernel<<<512, 256, 0, stream>>>(images, texts, Wti, Wtt, b_img, b_txt, cs_w,
                                       Fi, Ft, rni, siv, rnt, stv);
  sim_kernel<<<1024, 256, 65536, stream>>>(Fi, Ft, rni, siv, rnt, stv, cs_b, edge,
                                           out_final, out_sim, out_causal);
}

// Round 10
// 112.638 us; speedup vs baseline: 1.1540x; 1.0190x over previous
//
#include <hip/hip_runtime.h>
#include <hip/hip_bf16.h>

typedef __bf16 bf16_t;
typedef __bf16 bf16x8 __attribute__((ext_vector_type(8)));
typedef float f32x4 __attribute__((ext_vector_type(4)));

static constexpr int NB  = 4096;  // batch
static constexpr int KIN = 768;   // D_IN
static constexpr int DD  = 256;   // D

// ---------------------------------------------------------------------------
// Kernel 1: pack W (KIN x DD, f32) -> Wt (DD x KIN, bf16) via LDS transpose.
// ---------------------------------------------------------------------------
__global__ __launch_bounds__(256) void pack_wt_kernel(
    const float* __restrict__ Wi, const float* __restrict__ Wx,
    bf16_t* __restrict__ Oi, bf16_t* __restrict__ Ox)
{
  __shared__ bf16_t tile[64][66];
  const int b = blockIdx.x;
  const bool isTxt = (b >= 48);
  const int t = isTxt ? b - 48 : b;
  const float* W = isTxt ? Wx : Wi;
  bf16_t* O      = isTxt ? Ox : Oi;
  const int k0 = (t % 12) * 64;     // KIN/64 = 12
  const int c0 = (t / 12) * 64;     // DD/64  = 4
  const int cl = threadIdx.x & 63;
  const int rw = threadIdx.x >> 6;

#pragma unroll
  for (int p = 0; p < 16; ++p) {
    const int kl = p * 4 + rw;
    tile[kl][cl] = (bf16_t)W[(size_t)(k0 + kl) * DD + c0 + cl];
  }
  __syncthreads();
#pragma unroll
  for (int p = 0; p < 16; ++p) {
    const int clo = p * 4 + rw;
    O[(size_t)(c0 + clo) * KIN + k0 + cl] = tile[cl][clo];
  }
}

// ---------------------------------------------------------------------------
// Kernel 2: projection GEMM  F = X @ W + b   (4096 x 768 x 256), bf16 MFMA.
// 512 blocks (256 per matrix). Block = 16 rows; wave w = cols [w*64, w*64+64).
// ---------------------------------------------------------------------------
__global__ __launch_bounds__(256) void proj_kernel(
    const float* __restrict__ images, const float* __restrict__ texts,
    const bf16_t* __restrict__ Wti, const bf16_t* __restrict__ Wtt,
    const float* __restrict__ b_img, const float* __restrict__ b_txt,
    const float* __restrict__ cs_w,
    bf16_t* __restrict__ Fi, bf16_t* __restrict__ Ft,
    float* __restrict__ rni, float* __restrict__ si,
    float* __restrict__ rnt, float* __restrict__ st)
{
  __shared__ float lnsq[4][16];
  __shared__ float lsdt[4][16];

  const int bid = blockIdx.x;
  const bool isTxt = (bid >= 256);
  const float* X    = isTxt ? texts : images;
  const bf16_t* Wt  = isTxt ? Wtt : Wti;
  const float* bias = isTxt ? b_txt : b_img;
  const float* csw  = cs_w + (isTxt ? DD : 0);
  bf16_t* F     = isTxt ? Ft : Fi;
  float* rnorm  = isTxt ? rnt : rni;
  float* svec   = isTxt ? st : si;

  const int lane = threadIdx.x & 63;
  const int wave = threadIdx.x >> 6;
  const int lrow = lane & 15;
  const int g    = lane >> 4;
  const int rb   = (bid & 255) * 16;
  const int cwb  = wave * 64;

  const f32x4 fzero = {0.f, 0.f, 0.f, 0.f};
  f32x4 acc[4];
#pragma unroll
  for (int n = 0; n < 4; ++n) acc[n] = fzero;

  const float*  xp0 = X  + (size_t)(rb + lrow) * KIN + g * 8;
  const bf16_t* wp0 = Wt + (size_t)(cwb + lrow) * KIN + g * 8;

#pragma unroll 2
  for (int ks = 0; ks < KIN / 32; ++ks) {
    const float* xp = xp0 + ks * 32;
    f32x4 x0 = *reinterpret_cast<const f32x4*>(xp);
    f32x4 x1 = *reinterpret_cast<const f32x4*>(xp + 4);
    bf16x8 a;
#pragma unroll
    for (int e = 0; e < 4; ++e) { a[e] = (bf16_t)x0[e]; a[e + 4] = (bf16_t)x1[e]; }
#pragma unroll
    for (int n = 0; n < 4; ++n) {
      bf16x8 bfr = *reinterpret_cast<const bf16x8*>(wp0 + (size_t)n * 16 * KIN + ks * 32);
      acc[n] = __builtin_amdgcn_mfma_f32_16x16x32_bf16(a, bfr, acc[n], 0, 0, 0);
    }
  }

  float nsq[4] = {0.f, 0.f, 0.f, 0.f};
  float sdt[4] = {0.f, 0.f, 0.f, 0.f};
#pragma unroll
  for (int n = 0; n < 4; ++n) {
    const int col = cwb + n * 16 + lrow;
    const float bn = bias[col];
    const float wn = csw[col];
#pragma unroll
    for (int r = 0; r < 4; ++r) {
      float v = acc[n][r] + bn;
      const int row = rb + g * 4 + r;
      F[(size_t)row * DD + col] = (bf16_t)v;
      nsq[r] += v * v;
      sdt[r] += v * wn;
    }
  }
#pragma unroll
  for (int msk = 8; msk >= 1; msk >>= 1) {
#pragma unroll
    for (int r = 0; r < 4; ++r) {
      nsq[r] += __shfl_xor(nsq[r], msk, 64);
      sdt[r] += __shfl_xor(sdt[r], msk, 64);
    }
  }
  if (lrow == 0) {
#pragma unroll
    for (int r = 0; r < 4; ++r) {
      lnsq[wave][g * 4 + r] = nsq[r];
      lsdt[wave][g * 4 + r] = sdt[r];
    }
  }
  __syncthreads();
  if (threadIdx.x < 16) {
    float tn = 0.f, ts = 0.f;
#pragma unroll
    for (int w2 = 0; w2 < 4; ++w2) { tn += lnsq[w2][threadIdx.x]; ts += lsdt[w2][threadIdx.x]; }
    rnorm[rb + threadIdx.x] = 1.0f / sqrtf(tn);
    svec [rb + threadIdx.x] = ts;
  }
}

// ---------------------------------------------------------------------------
// Kernel 3: sim = Fi @ Ft^T (4096 x 4096 x 256) + fused epilogue.
// 128x128 tile, 1024 blocks, 4 waves (2x2) x 4x4 fragments, 64KB LDS bounce.
// R10 change vs R9: the FULL edge tile (64 floats/thread = 16x f32x4 NT
// loads) is issued BEFORE the GEMM K-loop (T14 async-stage): HBM latency
// hides under GEMM + LDS bounce, and the streaming epilogue becomes a pure
// store stream. __launch_bounds__(256,2) caps VGPR at 256 (no spill, and
// occupancy stays LDS-bound at 2 blocks/CU either way).
// ---------------------------------------------------------------------------
__global__ __launch_bounds__(256, 2) void sim_kernel(
    const bf16_t* __restrict__ Fi, const bf16_t* __restrict__ Ft,
    const float* __restrict__ rni, const float* __restrict__ si,
    const float* __restrict__ rnt, const float* __restrict__ st,
    const float* __restrict__ cs_b, const float* __restrict__ edge,
    float* __restrict__ out_final, float* __restrict__ out_sim,
    float* __restrict__ out_causal)
{
  extern __shared__ float smem[];   // 128*128 f32 = 64 KB, XOR-swizzled

  // XCD-aware swizzle: 1024 blocks, 8 XCDs -> contiguous 128-block chunks.
  const int bid = blockIdx.x;
  const int swz = (bid & 7) * 128 + (bid >> 3);
  const int bx = swz & 31;   // col tile
  const int by = swz >> 5;   // row tile

  const int tid  = threadIdx.x;
  const int lane = tid & 63;
  const int wave = tid >> 6;
  const int wr = wave >> 1;
  const int wc = wave & 1;
  const int lrow = lane & 15;
  const int g    = lane >> 4;

  const int rowG0 = by * 128;
  const int colG0 = bx * 128;
  const int rowBase = rowG0 + wr * 64;
  const int colBase = colG0 + wc * 64;

  // ---- async-stage: issue the whole edge tile up front (16 NT f32x4) ----
  f32x4 ewr[16];
#pragma unroll
  for (int it = 0; it < 16; ++it) {
    const int e = (it * 256 + tid) * 4;
    const int r = e >> 7;        // 0..127
    const int c = e & 127;       // multiple of 4
    ewr[it] = __builtin_nontemporal_load(
        reinterpret_cast<const f32x4*>(edge + (size_t)(rowG0 + r) * NB + colG0 + c));
  }
  asm volatile("" ::: "memory");   // pin prefetch issue before the K-loop

  const f32x4 fzero = {0.f, 0.f, 0.f, 0.f};
  f32x4 acc[4][4];
#pragma unroll
  for (int m = 0; m < 4; ++m)
#pragma unroll
    for (int n = 0; n < 4; ++n) acc[m][n] = fzero;

  const bf16_t* ap0 = Fi + (size_t)(rowBase + lrow) * DD + g * 8;
  const bf16_t* bp0 = Ft + (size_t)(colBase + lrow) * DD + g * 8;

#pragma unroll 2
  for (int ks = 0; ks < DD / 32; ++ks) {
    bf16x8 a[4], b[4];
#pragma unroll
    for (int m = 0; m < 4; ++m)
      a[m] = *reinterpret_cast<const bf16x8*>(ap0 + (size_t)m * 16 * DD + ks * 32);
#pragma unroll
    for (int n = 0; n < 4; ++n)
      b[n] = *reinterpret_cast<const bf16x8*>(bp0 + (size_t)n * 16 * DD + ks * 32);
#pragma unroll
    for (int m = 0; m < 4; ++m)
#pragma unroll
      for (int n = 0; n < 4; ++n)
        acc[m][n] = __builtin_amdgcn_mfma_f32_16x16x32_bf16(a[m], b[n], acc[m][n], 0, 0, 0);
  }

  // Scale factors for this wave's fragments.
  float rntv[4];
#pragma unroll
  for (int n = 0; n < 4; ++n) rntv[n] = rnt[colBase + n * 16 + lrow];
  float rnv[4][4];
#pragma unroll
  for (int m = 0; m < 4; ++m)
#pragma unroll
    for (int r = 0; r < 4; ++r) rnv[m][r] = rni[rowBase + m * 16 + g * 4 + r];

  // Fragment -> LDS (final sim values). XOR swizzle: col ^= (row&7)<<2.
#pragma unroll
  for (int m = 0; m < 4; ++m) {
#pragma unroll
    for (int n = 0; n < 4; ++n) {
#pragma unroll
      for (int r = 0; r < 4; ++r) {
        const int rl = wr * 64 + m * 16 + g * 4 + r;      // tile-local row
        const int cl = wc * 64 + n * 16 + lrow;           // tile-local col
        smem[rl * 128 + (cl ^ ((rl & 7) << 2))] = acc[m][n][r] * rnv[m][r] * rntv[n];
      }
    }
  }
  __syncthreads();

  // Streaming epilogue: pure store stream (edge already in registers).
  const float cb = cs_b[0];
#pragma unroll
  for (int it = 0; it < 16; ++it) {
    const int e = (it * 256 + tid) * 4;
    const int r = e >> 7;        // 0..127
    const int c = e & 127;       // multiple of 4
    const f32x4 sv4 = *reinterpret_cast<const f32x4*>(&smem[r * 128 + (c ^ ((r & 7) << 2))]);
    const float sir = si[rowG0 + r];
    const f32x4 st4 = *reinterpret_cast<const f32x4*>(st + colG0 + c);
    const size_t idx = (size_t)(rowG0 + r) * NB + colG0 + c;
    f32x4 ca4, fin4;
#pragma unroll
    for (int j = 0; j < 4; ++j) {
      const float strength = sir + st4[j] + cb;
      ca4[j]  = ewr[it][j] * strength;
      fin4[j] = sv4[j] + 0.3f * ca4[j];
    }
    *reinterpret_cast<f32x4*>(out_sim    + idx) = sv4;
    *reinterpret_cast<f32x4*>(out_causal + idx) = ca4;
    *reinterpret_cast<f32x4*>(out_final  + idx) = fin4;
  }
}

// ---------------------------------------------------------------------------
extern "C" void kernel_launch(void* const* d_in, const int* in_sizes, int n_in,
                              void* d_out, int out_size, void* d_ws, size_t ws_size,
                              hipStream_t stream) {
  const float* images = (const float*)d_in[0];
  const float* texts  = (const float*)d_in[1];
  const float* W_img  = (const float*)d_in[2];
  const float* b_img  = (const float*)d_in[3];
  const float* W_txt  = (const float*)d_in[4];
  const float* b_txt  = (const float*)d_in[5];
  const float* cs_w   = (const float*)d_in[6];
  const float* cs_b   = (const float*)d_in[7];
  const float* edge   = (const float*)d_in[8];

  float* out_final  = (float*)d_out;
  float* out_sim    = out_final + (size_t)NB * NB;
  float* out_causal = out_sim   + (size_t)NB * NB;

  // Workspace layout (~4.9 MiB total)
  char* ws = (char*)d_ws;
  bf16_t* Fi  = (bf16_t*)ws;                     // 4096*256 bf16
  bf16_t* Ft  = Fi  + (size_t)NB * DD;           // 4096*256 bf16
  bf16_t* Wti = Ft  + (size_t)NB * DD;           // 256*768 bf16
  bf16_t* Wtt = Wti + (size_t)DD * KIN;          // 256*768 bf16
  float*  rni = (float*)(Wtt + (size_t)DD * KIN);
  float*  siv = rni + NB;
  float*  rnt = siv + NB;
  float*  stv = rnt + NB;

  pack_wt_kernel<<<96, 256, 0, stream>>>(W_img, W_txt, Wti, Wtt);
  proj_kernel<<<512, 256, 0, stream>>>(images, texts, Wti, Wtt, b_img, b_txt, cs_w,
                                       Fi, Ft, rni, siv, rnt, stv);
  sim_kernel<<<1024, 256, 65536, stream>>>(Fi, Ft, rni, siv, rnt, stv, cs_b, edge,
                                           out_final, out_sim, out_causal);
}